// Round 6
// baseline (150.758 us; speedup 1.0000x reference)
//
#include <hip/hip_runtime.h>
#include <hip/hip_bf16.h>

#define NB 32
#define DIN 512
#define TT 4096
#define DH 500
#define DHP 512
#define EPSV 1e-12f
#define BM 64
#define LDA 520            // bf16 elems; 1040B row stride, 16B-aligned rows
#define NTILES (TT / BM)   // 64 t-tiles per batch
#define TPB 8              // tiles per block (pipelined)

typedef short short8 __attribute__((ext_vector_type(8)));
typedef float f32x16 __attribute__((ext_vector_type(16)));

__device__ inline unsigned short f2bf(float f) {
    unsigned int u = __builtin_bit_cast(unsigned int, f);
    unsigned int r = (u + 0x7fffu + ((u >> 16) & 1u)) >> 16;
    return (unsigned short)r;
}
__device__ inline float bf2f(unsigned short h) {
    unsigned int u = ((unsigned int)h) << 16;
    return __builtin_bit_cast(float, u);
}

// Kernel 0: pack w1 -> bf16 MFMA-fragment order [hb=16][ks=32][lane=64][8]
//   h = hb*32 + (lane&31),  d = ks*16 + (lane>>5)*8 + j
__global__ void prep_kernel(const float* __restrict__ w1, const float* __restrict__ w2,
                            unsigned short* __restrict__ w1b, float* __restrict__ w2f) {
    int idx = blockIdx.x * blockDim.x + threadIdx.x;
    if (idx < DHP * DIN) {
        const int j    = idx & 7;
        const int lane = (idx >> 3) & 63;
        const int ks   = (idx >> 9) & 31;
        const int hb   = idx >> 14;
        const int h = hb * 32 + (lane & 31);
        const int d = ks * 16 + (lane >> 5) * 8 + j;
        float v = (h < DH) ? w1[h * DIN + d] : 0.f;
        w1b[idx] = f2bf(v);
        if (idx < DHP) w2f[idx] = (idx < DH) ? w2[idx] : 0.f;
    }
}

// Kernel 1 (fused, pipelined): one block per (b, group of 8 t-tiles).
// Double-buffered LDS; global loads for tile i+1 issued before MFMA of
// tile i (latency hides under compute); ds_writes land after phase 4.
__launch_bounds__(512, 2)
__global__ void scores_fused(const float* __restrict__ x,
                             const unsigned short* __restrict__ w1b,
                             const float* __restrict__ w2f,
                             float* __restrict__ pm, float* __restrict__ pz,
                             float* __restrict__ pswx, float* __restrict__ psx,
                             float* __restrict__ psx2) {
    __shared__ unsigned short A_lds[2][BM][LDA];
    __shared__ float score_p[8][BM];
    __shared__ float w_lds[2][BM];

    const int tid = threadIdx.x;
    const int b  = blockIdx.x >> 3;
    const int tg = blockIdx.x & 7;             // tile group: tiles tg*8 .. tg*8+7

    const int ts = tid & 63;                   // staging: t within tile
    const int dg = tid >> 6;                   // staging: d-group (64 d each)

    const int w = tid >> 6;                    // wave id: h-panels {2w,2w+1}
    const int lane = tid & 63;
    const int lane31 = lane & 31;
    const int khalf = lane >> 5;
    const int hrow0 = w * 64;

    // hoist w2 weights (reused for all 8 tiles)
    float w20v[16], w21v[16];
    #pragma unroll
    for (int g = 0; g < 16; ++g) {
        const int rp = (g & 3) + 8 * (g >> 2) + 4 * khalf;
        w20v[g] = w2f[hrow0 + rp];
        w21v[g] = w2f[hrow0 + 32 + rp];
    }

    const float* xbase = x + (size_t)b * DIN * TT;
    const unsigned short* base0 = w1b + (size_t)w * 32768 + (size_t)lane * 8;
    const unsigned short* base1 = base0 + 16384;

    // ---- Prologue: stage tile 0 into buffer 0 ----
    {
        const float* xb = xbase + (size_t)(tg * TPB) * BM + ts;
        #pragma unroll
        for (int oct = 0; oct < 8; ++oct) {
            short8 pk;
            #pragma unroll
            for (int j = 0; j < 8; ++j)
                pk[j] = (short)f2bf(xb[(size_t)(dg * 64 + oct * 8 + j) * TT]);
            *reinterpret_cast<short8*>(&A_lds[0][ts][dg * 64 + oct * 8]) = pk;
        }
    }
    __syncthreads();

    for (int i = 0; i < TPB; ++i) {
        const int buf = i & 1;
        const bool more = (i + 1 < TPB);

        // ---- issue prefetch loads for tile i+1 (latency hides under MFMA) ----
        float xr[64];
        if (more) {
            const float* xb = xbase + (size_t)(tg * TPB + i + 1) * BM + ts;
            #pragma unroll
            for (int oct = 0; oct < 8; ++oct)
                #pragma unroll
                for (int j = 0; j < 8; ++j)
                    xr[oct * 8 + j] = xb[(size_t)(dg * 64 + oct * 8 + j) * TT];
        }

        // ---- MFMA: A=w1 (m=h), B=x^T (n=t); D rows=h in-lane reduce ----
        f32x16 acc00, acc01, acc10, acc11;
        #pragma unroll
        for (int g = 0; g < 16; ++g) { acc00[g] = 0.f; acc01[g] = 0.f; acc10[g] = 0.f; acc11[g] = 0.f; }

        const unsigned short* Bp0 = &A_lds[buf][lane31][khalf * 8];
        const unsigned short* Bp1 = &A_lds[buf][32 + lane31][khalf * 8];

        #pragma unroll 4
        for (int ks = 0; ks < 32; ++ks) {
            short8 a0 = *reinterpret_cast<const short8*>(base0 + ks * 512);
            short8 a1 = *reinterpret_cast<const short8*>(base1 + ks * 512);
            short8 b0 = *reinterpret_cast<const short8*>(Bp0 + ks * 16);
            short8 b1 = *reinterpret_cast<const short8*>(Bp1 + ks * 16);
            acc00 = __builtin_amdgcn_mfma_f32_32x32x16_bf16(a0, b0, acc00, 0, 0, 0);
            acc01 = __builtin_amdgcn_mfma_f32_32x32x16_bf16(a0, b1, acc01, 0, 0, 0);
            acc10 = __builtin_amdgcn_mfma_f32_32x32x16_bf16(a1, b0, acc10, 0, 0, 0);
            acc11 = __builtin_amdgcn_mfma_f32_32x32x16_bf16(a1, b1, acc11, 0, 0, 0);
        }

        float s0 = 0.f, s1 = 0.f;
        #pragma unroll
        for (int g = 0; g < 16; ++g) {
            s0 += fmaxf(acc00[g], 0.f) * w20v[g] + fmaxf(acc10[g], 0.f) * w21v[g];
            s1 += fmaxf(acc01[g], 0.f) * w20v[g] + fmaxf(acc11[g], 0.f) * w21v[g];
        }
        s0 += __shfl_xor(s0, 32, 64);
        s1 += __shfl_xor(s1, 32, 64);
        if (khalf == 0) {
            score_p[w][lane31] = s0;
            score_p[w][32 + lane31] = s1;
        }
        __syncthreads();

        // ---- softmax partial (wave 0) ----
        if (tid < BM) {
            float s = 0.f;
            #pragma unroll
            for (int ww = 0; ww < 8; ++ww) s += score_p[ww][tid];
            float m = s;
            #pragma unroll
            for (int k = 1; k <= 32; k <<= 1) m = fmaxf(m, __shfl_xor(m, k, 64));
            float e = __expf(s - m);
            float Z = e;
            #pragma unroll
            for (int k = 1; k <= 32; k <<= 1) Z += __shfl_xor(Z, k, 64);
            w_lds[buf][tid] = e;
            if (tid == 0) {
                const size_t gt = (size_t)blockIdx.x * TPB + i;
                pm[gt] = m; pz[gt] = Z;
            }
        }
        __syncthreads();

        // ---- phase 4: per-d partials over this tile's 64 t ----
        {
            const int d = tid;
            float sx = 0.f, sx2 = 0.f, swx = 0.f;
            #pragma unroll 8
            for (int t = 0; t < BM; ++t) {
                const float xv = bf2f(A_lds[buf][t][d]);
                const float wv = w_lds[buf][t];
                sx += xv; sx2 += xv * xv; swx += wv * xv;
            }
            const size_t o = ((size_t)blockIdx.x * TPB + i) * DHP + d;
            psx[o] = sx; psx2[o] = sx2; pswx[o] = swx;
        }

        // ---- write prefetched tile into the other buffer ----
        if (more) {
            #pragma unroll
            for (int oct = 0; oct < 8; ++oct) {
                short8 pk;
                #pragma unroll
                for (int j = 0; j < 8; ++j) pk[j] = (short)f2bf(xr[oct * 8 + j]);
                *reinterpret_cast<short8*>(&A_lds[buf ^ 1][ts][dg * 64 + oct * 8]) = pk;
            }
        }
        __syncthreads();
    }
}

// Kernel 2: combine 64 tiles per batch -> mean, stddev
__global__ void combine_kernel(const float* __restrict__ pm, const float* __restrict__ pz,
                               const float* __restrict__ pswx, const float* __restrict__ psx,
                               const float* __restrict__ psx2, float* __restrict__ out) {
    __shared__ float sm[NTILES], sz[NTILES];
    const int b = blockIdx.x;
    const int tid = threadIdx.x;               // d = tid, 0..511
    if (tid < NTILES) { sm[tid] = pm[b * NTILES + tid]; sz[tid] = pz[b * NTILES + tid]; }
    __syncthreads();

    float mg = -1e30f;
    #pragma unroll 8
    for (int i = 0; i < NTILES; ++i) mg = fmaxf(mg, sm[i]);
    float denom = 0.f;
    #pragma unroll 8
    for (int i = 0; i < NTILES; ++i) denom += sz[i] * __expf(sm[i] - mg);

    float num = 0.f, sx = 0.f, sx2 = 0.f;
    #pragma unroll 4
    for (int i = 0; i < NTILES; ++i) {
        const size_t o = ((size_t)(b * NTILES + i)) * DHP + tid;
        const float f = __expf(sm[i] - mg);
        num += f * pswx[o];
        sx  += psx[o];
        sx2 += psx2[o];
    }
    const float mean = num / denom;
    const float ex  = sx  * (1.f / TT);
    const float ex2 = sx2 * (1.f / TT);
    float var = ex2 - 2.f * mean * ex + mean * mean;
    if (var <= EPSV) var = EPSV;
    out[(size_t)b * 1024 + tid] = mean;
    out[(size_t)b * 1024 + 512 + tid] = sqrtf(var);
}

extern "C" void kernel_launch(void* const* d_in, const int* in_sizes, int n_in,
                              void* d_out, int out_size, void* d_ws, size_t ws_size,
                              hipStream_t stream) {
    const float* x  = (const float*)d_in[0];
    const float* w1 = (const float*)d_in[1];
    const float* w2 = (const float*)d_in[2];
    float* out = (float*)d_out;

    char* ws = (char*)d_ws;
    unsigned short* w1b = (unsigned short*)ws;                    // 512 KB
    float* w2f  = (float*)(ws + 524288);                          // 2 KB
    float* pm   = (float*)(ws + 526336);                          // 8 KB
    float* pz   = (float*)(ws + 534528);                          // 8 KB
    float* pswx = (float*)(ws + 542720);                          // 4 MB
    float* psx  = pswx + (size_t)NB * NTILES * DHP;               // 4 MB
    float* psx2 = psx  + (size_t)NB * NTILES * DHP;               // 4 MB

    prep_kernel<<<(DHP * DIN + 255) / 256, 256, 0, stream>>>(w1, w2, w1b, w2f);
    scores_fused<<<NB * TPB, 512, 0, stream>>>(x, w1b, w2f, pm, pz, pswx, psx, psx2);
    combine_kernel<<<NB, 512, 0, stream>>>(pm, pz, pswx, psx, psx2, out);
}

// Round 7
// 140.325 us; speedup vs baseline: 1.0743x; 1.0743x over previous
//
#include <hip/hip_runtime.h>
#include <hip/hip_bf16.h>

#define NB 32
#define DIN 512
#define TT 4096
#define DH 500
#define DHP 512
#define EPSV 1e-12f
#define BM 64
#define LDA 520            // bf16 elems; 1040B row stride, 16B-aligned rows
#define NTILES (TT / BM)   // 64 t-tiles per batch

typedef short short8 __attribute__((ext_vector_type(8)));
typedef float f32x16 __attribute__((ext_vector_type(16)));
typedef float f32x4 __attribute__((ext_vector_type(4)));

__device__ inline unsigned short f2bf(float f) {
    unsigned int u = __builtin_bit_cast(unsigned int, f);
    unsigned int r = (u + 0x7fffu + ((u >> 16) & 1u)) >> 16;
    return (unsigned short)r;
}
__device__ inline float bf2f(unsigned short h) {
    unsigned int u = ((unsigned int)h) << 16;
    return __builtin_bit_cast(float, u);
}

// Kernel 0: pack w1 -> bf16 MFMA-fragment order [hb=16][ks=32][lane=64][8]
//   h = hb*32 + (lane&31),  d = ks*16 + (lane>>5)*8 + j
__global__ void prep_kernel(const float* __restrict__ w1, const float* __restrict__ w2,
                            unsigned short* __restrict__ w1b, float* __restrict__ w2f) {
    int idx = blockIdx.x * blockDim.x + threadIdx.x;
    if (idx < DHP * DIN) {
        const int j    = idx & 7;
        const int lane = (idx >> 3) & 63;
        const int ks   = (idx >> 9) & 31;
        const int hb   = idx >> 14;
        const int h = hb * 32 + (lane & 31);
        const int d = ks * 16 + (lane >> 5) * 8 + j;
        float v = (h < DH) ? w1[h * DIN + d] : 0.f;
        w1b[idx] = f2bf(v);
        if (idx < DHP) w2f[idx] = (idx < DH) ? w2[idx] : 0.f;
    }
}

// Kernel 1 (fused): per (b, 64-t tile): scores -> block softmax partial ->
// per-d partials (sx, sx2, swx). Stage phase uses float4 loads (16/thread,
// two 8-load batches all in flight) + cvt_pk_bf16 + scattered b16 LDS writes.
__launch_bounds__(512, 4)
__global__ void scores_fused(const float* __restrict__ x,
                             const unsigned short* __restrict__ w1b,
                             const float* __restrict__ w2f,
                             float* __restrict__ pm, float* __restrict__ pz,
                             float* __restrict__ pswx, float* __restrict__ psx,
                             float* __restrict__ psx2) {
    __shared__ unsigned short A_lds[BM][LDA];
    __shared__ float score_p[8][BM];
    __shared__ float w_lds[BM];

    const int tid = threadIdx.x;
    const int b = blockIdx.x >> 6;             // NTILES = 64 tiles per batch
    const int t0 = (blockIdx.x & 63) * BM;

    // ---- Phase 1: stage x[b, :, t0..t0+63] -> A_lds[t][d] (bf16) ----
    // thread: q = tid&15 (t-quad), dr = tid>>4 (d-row in 32-row pass).
    // 16 passes (h) of d; float4 = 4 consecutive t.
    {
        const int q  = tid & 15;
        const int dr = tid >> 4;
        const float* xb = x + (size_t)b * DIN * TT + t0 + 4 * q;

        f32x4 va[8], vb[8];
        #pragma unroll
        for (int h = 0; h < 8; ++h)
            va[h] = *reinterpret_cast<const f32x4*>(xb + (size_t)(h * 32 + dr) * TT);
        #pragma unroll
        for (int h = 0; h < 8; ++h)
            vb[h] = *reinterpret_cast<const f32x4*>(xb + (size_t)((h + 8) * 32 + dr) * TT);

        #pragma unroll
        for (int h = 0; h < 8; ++h) {
            const int d = h * 32 + dr;
            unsigned int p01, p23;
            asm("v_cvt_pk_bf16_f32 %0, %1, %2" : "=v"(p01) : "v"(va[h][0]), "v"(va[h][1]));
            asm("v_cvt_pk_bf16_f32 %0, %1, %2" : "=v"(p23) : "v"(va[h][2]), "v"(va[h][3]));
            A_lds[4 * q + 0][d] = (unsigned short)(p01 & 0xffffu);
            A_lds[4 * q + 1][d] = (unsigned short)(p01 >> 16);
            A_lds[4 * q + 2][d] = (unsigned short)(p23 & 0xffffu);
            A_lds[4 * q + 3][d] = (unsigned short)(p23 >> 16);
        }
        #pragma unroll
        for (int h = 0; h < 8; ++h) {
            const int d = (h + 8) * 32 + dr;
            unsigned int p01, p23;
            asm("v_cvt_pk_bf16_f32 %0, %1, %2" : "=v"(p01) : "v"(vb[h][0]), "v"(vb[h][1]));
            asm("v_cvt_pk_bf16_f32 %0, %1, %2" : "=v"(p23) : "v"(vb[h][2]), "v"(vb[h][3]));
            A_lds[4 * q + 0][d] = (unsigned short)(p01 & 0xffffu);
            A_lds[4 * q + 1][d] = (unsigned short)(p01 >> 16);
            A_lds[4 * q + 2][d] = (unsigned short)(p23 & 0xffffu);
            A_lds[4 * q + 3][d] = (unsigned short)(p23 >> 16);
        }
    }
    __syncthreads();

    // ---- Phase 2: MFMA. Wave w owns h-panels {2w,2w+1}; A=w1 (m=h),
    // B=x^T (n=t): D cols (lane&31)=t, rows=h -> relu*w2 reduce in-lane.
    const int w = tid >> 6;
    const int lane = tid & 63;
    const int lane31 = lane & 31;
    const int khalf = lane >> 5;
    const int hrow0 = w * 64;

    float w20v[16], w21v[16];
    #pragma unroll
    for (int g = 0; g < 16; ++g) {
        const int rp = (g & 3) + 8 * (g >> 2) + 4 * khalf;
        w20v[g] = w2f[hrow0 + rp];
        w21v[g] = w2f[hrow0 + 32 + rp];
    }

    f32x16 acc00, acc01, acc10, acc11;
    #pragma unroll
    for (int g = 0; g < 16; ++g) { acc00[g] = 0.f; acc01[g] = 0.f; acc10[g] = 0.f; acc11[g] = 0.f; }

    const unsigned short* base0 = w1b + (size_t)w * 32768 + (size_t)lane * 8;
    const unsigned short* base1 = base0 + 16384;
    const unsigned short* Bp0 = &A_lds[lane31][khalf * 8];
    const unsigned short* Bp1 = &A_lds[32 + lane31][khalf * 8];

    #pragma unroll 4
    for (int ks = 0; ks < 32; ++ks) {
        short8 a0 = *reinterpret_cast<const short8*>(base0 + ks * 512);
        short8 a1 = *reinterpret_cast<const short8*>(base1 + ks * 512);
        short8 b0 = *reinterpret_cast<const short8*>(Bp0 + ks * 16);
        short8 b1 = *reinterpret_cast<const short8*>(Bp1 + ks * 16);
        acc00 = __builtin_amdgcn_mfma_f32_32x32x16_bf16(a0, b0, acc00, 0, 0, 0);
        acc01 = __builtin_amdgcn_mfma_f32_32x32x16_bf16(a0, b1, acc01, 0, 0, 0);
        acc10 = __builtin_amdgcn_mfma_f32_32x32x16_bf16(a1, b0, acc10, 0, 0, 0);
        acc11 = __builtin_amdgcn_mfma_f32_32x32x16_bf16(a1, b1, acc11, 0, 0, 0);
    }

    float s0 = 0.f, s1 = 0.f;
    #pragma unroll
    for (int g = 0; g < 16; ++g) {
        s0 += fmaxf(acc00[g], 0.f) * w20v[g] + fmaxf(acc10[g], 0.f) * w21v[g];
        s1 += fmaxf(acc01[g], 0.f) * w20v[g] + fmaxf(acc11[g], 0.f) * w21v[g];
    }
    s0 += __shfl_xor(s0, 32, 64);
    s1 += __shfl_xor(s1, 32, 64);
    if (khalf == 0) {                          // deterministic per-wave partials
        score_p[w][lane31] = s0;
        score_p[w][32 + lane31] = s1;
    }
    __syncthreads();

    // ---- Phase 3: wave 0 finalizes scores -> e_t, m_blk, Z_blk ----
    if (tid < BM) {
        float s = 0.f;
        #pragma unroll
        for (int ww = 0; ww < 8; ++ww) s += score_p[ww][tid];
        float m = s;
        #pragma unroll
        for (int k = 1; k <= 32; k <<= 1) m = fmaxf(m, __shfl_xor(m, k, 64));
        float e = __expf(s - m);
        float Z = e;
        #pragma unroll
        for (int k = 1; k <= 32; k <<= 1) Z += __shfl_xor(Z, k, 64);
        w_lds[tid] = e;
        if (tid == 0) { pm[blockIdx.x] = m; pz[blockIdx.x] = Z; }
    }
    __syncthreads();

    // ---- Phase 4: per-d partials over the tile's 64 t ----
    {
        const int d = tid;                     // 0..511
        float sx = 0.f, sx2 = 0.f, swx = 0.f;
        #pragma unroll 8
        for (int t = 0; t < BM; ++t) {
            const float xv = bf2f(A_lds[t][d]);
            const float wv = w_lds[t];
            sx += xv; sx2 += xv * xv; swx += wv * xv;
        }
        const size_t o = (size_t)blockIdx.x * DHP + d;
        psx[o] = sx; psx2[o] = sx2; pswx[o] = swx;
    }
}

// Kernel 2: combine 64 tiles per batch -> mean, stddev
__global__ void combine_kernel(const float* __restrict__ pm, const float* __restrict__ pz,
                               const float* __restrict__ pswx, const float* __restrict__ psx,
                               const float* __restrict__ psx2, float* __restrict__ out) {
    __shared__ float sm[NTILES], sz[NTILES];
    const int b = blockIdx.x;
    const int tid = threadIdx.x;               // d = tid, 0..511
    if (tid < NTILES) { sm[tid] = pm[b * NTILES + tid]; sz[tid] = pz[b * NTILES + tid]; }
    __syncthreads();

    float mg = -1e30f;
    #pragma unroll 8
    for (int i = 0; i < NTILES; ++i) mg = fmaxf(mg, sm[i]);
    float denom = 0.f;
    #pragma unroll 8
    for (int i = 0; i < NTILES; ++i) denom += sz[i] * __expf(sm[i] - mg);

    float num = 0.f, sx = 0.f, sx2 = 0.f;
    #pragma unroll 4
    for (int i = 0; i < NTILES; ++i) {
        const size_t o = ((size_t)(b * NTILES + i)) * DHP + tid;
        const float f = __expf(sm[i] - mg);
        num += f * pswx[o];
        sx  += psx[o];
        sx2 += psx2[o];
    }
    const float mean = num / denom;
    const float ex  = sx  * (1.f / TT);
    const float ex2 = sx2 * (1.f / TT);
    float var = ex2 - 2.f * mean * ex + mean * mean;
    if (var <= EPSV) var = EPSV;
    out[(size_t)b * 1024 + tid] = mean;
    out[(size_t)b * 1024 + 512 + tid] = sqrtf(var);
}

extern "C" void kernel_launch(void* const* d_in, const int* in_sizes, int n_in,
                              void* d_out, int out_size, void* d_ws, size_t ws_size,
                              hipStream_t stream) {
    const float* x  = (const float*)d_in[0];
    const float* w1 = (const float*)d_in[1];
    const float* w2 = (const float*)d_in[2];
    float* out = (float*)d_out;

    char* ws = (char*)d_ws;
    unsigned short* w1b = (unsigned short*)ws;                    // 512 KB
    float* w2f  = (float*)(ws + 524288);                          // 2 KB
    float* pm   = (float*)(ws + 526336);                          // 8 KB
    float* pz   = (float*)(ws + 534528);                          // 8 KB
    float* pswx = (float*)(ws + 542720);                          // 4 MB
    float* psx  = pswx + (size_t)NB * NTILES * DHP;               // 4 MB
    float* psx2 = psx  + (size_t)NB * NTILES * DHP;               // 4 MB

    prep_kernel<<<(DHP * DIN + 255) / 256, 256, 0, stream>>>(w1, w2, w1b, w2f);
    scores_fused<<<NB * NTILES, 512, 0, stream>>>(x, w1b, w2f, pm, pz, pswx, psx, psx2);
    combine_kernel<<<NB, 512, 0, stream>>>(pm, pz, pswx, psx, psx2, out);
}